// Round 2
// baseline (108.218 us; speedup 1.0000x reference)
//
#include <hip/hip_runtime.h>

#define M_TOTAL 16384
#define N_TOTAL 1024
#define K_TOTAL 1024
#define BM 256
#define BN 128
#define BK 64
#define NTHREADS 512
#define NBN (N_TOTAL / BN)                 // 8
#define NWG ((M_TOTAL / BM) * NBN)         // 512

using f32x4  = __attribute__((ext_vector_type(4))) float;
using bf16x8 = __attribute__((ext_vector_type(8))) short;

// Pack two fp32 -> two bf16 (round-half-up: error <= 1 ulp_bf16, bias 2^-25
// relative). 2 adds + pack (compiler emits v_perm_b32) ~= 1.5 VALU/elem vs
// ~5 for full RNE bit-twiddle. Output error ~0.02 << 0.06375 threshold.
__device__ __forceinline__ unsigned pack2bf(float a, float b) {
    unsigned ua = __builtin_bit_cast(unsigned, a);
    unsigned ub = __builtin_bit_cast(unsigned, b);
    return ((ua + 0x8000u) >> 16) | ((ub + 0x8000u) & 0xffff0000u);
}

// C[m][n] = sum_k X[m][k]*W[n][k] + bias[n]
// 256x128 tile, BK=64, 8 waves (4x2, each 64x64). XOR-swizzled bf16 LDS.
__global__ __launch_bounds__(NTHREADS, 4) void gemm_bias_kernel(
    const float* __restrict__ X, const float* __restrict__ W,
    const float* __restrict__ bias, float* __restrict__ C)
{
    __shared__ short As[BM * BK];   // 32 KB
    __shared__ short Bs[BN * BK];   // 16 KB

    const int tid  = threadIdx.x;
    const int lane = tid & 63;
    const int wave = tid >> 6;      // 0..7
    const int wr = wave >> 1;       // 0..3: 64-row strip
    const int wc = wave & 1;        // 0..1: 64-col strip

    // XCD-chunked swizzle (NWG=512 divisible by 8): XCD x gets works
    // [x*64, x*64+64) = bm panels x*8..x*8+7, each panel's 8 bn-blocks
    // co-resident on one XCD -> X panel fetched ~once into that L2.
    const int bid  = blockIdx.x;
    const int work = (bid & 7) * (NWG / 8) + (bid >> 3);
    const int bm = work >> 3;       // work / NBN
    const int bn = work & (NBN - 1);
    const int m0 = bm * BM, n0 = bn * BN;

    const int srow  = tid >> 4;     // 0..31
    const int scol4 = tid & 15;     // float4 index along K

    f32x4 acc[4][4] = {};
    char* const Ab = (char*)As;
    char* const Bb = (char*)Bs;

    for (int k0 = 0; k0 < K_TOTAL; k0 += BK) {
        __syncthreads();            // previous iteration's reads complete
        #pragma unroll
        for (int p = 0; p < 8; ++p) {
            const int row = srow + p * 32;
            const f32x4 v = *(const f32x4*)(X + (size_t)(m0 + row) * K_TOTAL + k0 + scol4 * 4);
            uint2 wv;
            wv.x = pack2bf(v[0], v[1]);
            wv.y = pack2bf(v[2], v[3]);
            // element [row][k] at byte (row*128 + 2k) ^ ((row&7)<<4):
            // breaks the 16-way bank conflict of 128B-stride rows.
            *(uint2*)(Ab + ((row * (BK * 2) + scol4 * 8) ^ ((row & 7) << 4))) = wv;
        }
        #pragma unroll
        for (int p = 0; p < 4; ++p) {
            const int row = srow + p * 32;
            const f32x4 v = *(const f32x4*)(W + (size_t)(n0 + row) * K_TOTAL + k0 + scol4 * 4);
            uint2 wv;
            wv.x = pack2bf(v[0], v[1]);
            wv.y = pack2bf(v[2], v[3]);
            *(uint2*)(Bb + ((row * (BK * 2) + scol4 * 8) ^ ((row & 7) << 4))) = wv;
        }
        __syncthreads();

        #pragma unroll
        for (int ks = 0; ks < 2; ++ks) {
            const int kel = ks * 32 + ((lane >> 4) << 3);   // k base for this lane
            bf16x8 af[4], bfr[4];
            #pragma unroll
            for (int i = 0; i < 4; ++i) {
                const int arow = wr * 64 + i * 16 + (lane & 15);
                af[i]  = *(const bf16x8*)(Ab + ((arow * (BK * 2) + kel * 2) ^ ((arow & 7) << 4)));
                const int brow = wc * 64 + i * 16 + (lane & 15);
                bfr[i] = *(const bf16x8*)(Bb + ((brow * (BK * 2) + kel * 2) ^ ((brow & 7) << 4)));
            }
            #pragma unroll
            for (int mi = 0; mi < 4; ++mi) {
                #pragma unroll
                for (int ni = 0; ni < 4; ++ni) {
                    acc[mi][ni] = __builtin_amdgcn_mfma_f32_16x16x32_bf16(
                        af[mi], bfr[ni], acc[mi][ni], 0, 0, 0);
                }
            }
        }
    }

    // epilogue: D element (row=(lane>>4)*4+r, col=lane&15)  [m89-verified]
    const int cl = lane & 15;
    const int r0 = (lane >> 4) * 4;
    #pragma unroll
    for (int ni = 0; ni < 4; ++ni) {
        const int n = n0 + wc * 64 + ni * 16 + cl;
        const float bvv = bias[n];
        #pragma unroll
        for (int mi = 0; mi < 4; ++mi) {
            const int m = m0 + wr * 64 + mi * 16 + r0;
            #pragma unroll
            for (int r = 0; r < 4; ++r) {
                C[(size_t)(m + r) * N_TOTAL + n] = acc[mi][ni][r] + bvv;
            }
        }
    }
}

extern "C" void kernel_launch(void* const* d_in, const int* in_sizes, int n_in,
                              void* d_out, int out_size, void* d_ws, size_t ws_size,
                              hipStream_t stream) {
    // inputs: 0:X 1:Wq 2:bq 3:Wk 4:bk 5:Wv 6:bv
    // softmax rows sum to 1 => out = X @ Wv^T + bv exactly.
    const float* X  = (const float*)d_in[0];
    const float* Wv = (const float*)d_in[5];
    const float* bv = (const float*)d_in[6];
    float* out = (float*)d_out;

    gemm_bias_kernel<<<dim3(NWG), dim3(NTHREADS), 0, stream>>>(X, Wv, bv, out);
}

// Round 3
// 77.216 us; speedup vs baseline: 1.4015x; 1.4015x over previous
//
#include <hip/hip_runtime.h>
#include <stdint.h>

#define M_TOTAL 16384
#define N_TOTAL 1024
#define K_TOTAL 1024
#define BM 128
#define BN 128
#define BK 64
#define NBN (N_TOTAL / BN)                  // 8
#define NWG ((M_TOTAL / BM) * NBN)          // 1024

using f32x4  = __attribute__((ext_vector_type(4))) float;
using bf16x8 = __attribute__((ext_vector_type(8))) short;
using bf16x4 = __attribute__((ext_vector_type(4))) short;

__device__ __forceinline__ unsigned packrne(float x, float y) {
    // two fp32 -> packed bf16 pair, round-to-nearest-even
    unsigned ux = __builtin_bit_cast(unsigned, x);
    unsigned uy = __builtin_bit_cast(unsigned, y);
    ux += 0x7fffu + ((ux >> 16) & 1u);
    uy += 0x7fffu + ((uy >> 16) & 1u);
    return (ux >> 16) | (uy & 0xffff0000u);
}

// ---------------- kernel 1: fp32 -> bf16 stream convert (8 elems/thread) ----
__global__ __launch_bounds__(256) void cvt_bf16_kernel(
    const float* __restrict__ in, uint4* __restrict__ out, int n8)
{
    const int i = blockIdx.x * 256 + threadIdx.x;
    if (i >= n8) return;
    const f32x4* p = (const f32x4*)in + (size_t)i * 2;
    const f32x4 a = p[0], b = p[1];
    uint4 r;
    r.x = packrne(a[0], a[1]);
    r.y = packrne(a[2], a[3]);
    r.z = packrne(b[0], b[1]);
    r.w = packrne(b[2], b[3]);
    out[i] = r;
}

// ---------------- kernel 2: m97-recipe bf16 GEMM + bias ---------------------
// C[m][n] = sum_k Xb[m][k]*Wb[n][k] + bias[n]; Xb/Wb bf16 row-major.
// 128x128 tile, BK=64, 4 waves (each 64x64 = 4x4 16x16x32 frags).
// Linear LDS + global_load_lds width=16 (m97 structure, 874-912 TF verified).
__global__ __launch_bounds__(256) void gemm_lds_kernel(
    const unsigned short* __restrict__ Xb, const unsigned short* __restrict__ Wb,
    const float* __restrict__ bias, float* __restrict__ C)
{
    __shared__ short As[BM * BK];   // 16 KB, linear [row][k]
    __shared__ short Bs[BN * BK];   // 16 KB

    const int tid  = threadIdx.x;
    const int lane = tid & 63;
    const int wave = tid >> 6;      // 0..3
    const int wr = wave >> 1;       // 64-row strip
    const int wc = wave & 1;        // 64-col strip

    // XCD-chunked swizzle (NWG=1024, %8==0): one bm-panel's 8 bn-blocks
    // co-resident on one XCD -> X panel fetched ~once (round-2 verified:
    // FETCH 266->61 MB).
    const int bid  = blockIdx.x;
    const int work = (bid & 7) * (NWG / 8) + (bid >> 3);
    const int bm = work >> 3;
    const int bn = work & 7;
    const int m0 = bm * BM, n0 = bn * BN;

    // staging geometry: issue s covers rows [s*32, s*32+32); within an issue,
    // wave w writes LDS bytes [s*4096 + w*1024, +1024) = rows w*8..w*8+7.
    // HW scatters lane i at base + i*16; matching per-lane global source:
    const int srow = wave * 8 + (lane >> 3);    // row within 32-row stripe
    const int scol = (lane & 7) * 8;            // k element offset (8 bf16 = 16B)

    f32x4 acc[4][4] = {};

    #pragma unroll 1
    for (int k0 = 0; k0 < K_TOTAL; k0 += BK) {
        __syncthreads();            // previous iteration's ds_reads complete
        #pragma unroll
        for (int s = 0; s < 4; ++s) {
            __builtin_amdgcn_global_load_lds(
                (const __attribute__((address_space(1))) void*)
                    (Xb + (size_t)(m0 + s * 32 + srow) * K_TOTAL + k0 + scol),
                (__attribute__((address_space(3))) void*)
                    ((char*)As + s * 4096 + wave * 1024),
                16, 0, 0);
        }
        #pragma unroll
        for (int s = 0; s < 4; ++s) {
            __builtin_amdgcn_global_load_lds(
                (const __attribute__((address_space(1))) void*)
                    (Wb + (size_t)(n0 + s * 32 + srow) * K_TOTAL + k0 + scol),
                (__attribute__((address_space(3))) void*)
                    ((char*)Bs + s * 4096 + wave * 1024),
                16, 0, 0);
        }
        __syncthreads();            // compiler drains vmcnt(0) here (m97 stall, accepted)

        #pragma unroll
        for (int ks = 0; ks < 2; ++ks) {
            const int kel = ks * 32 + ((lane >> 4) << 3);   // lane's k base
            bf16x8 af[4], bfr[4];
            #pragma unroll
            for (int i = 0; i < 4; ++i) {
                const int arow = wr * 64 + i * 16 + (lane & 15);
                af[i]  = *(const bf16x8*)((char*)As + arow * (BK * 2) + kel * 2);
                const int brow = wc * 64 + i * 16 + (lane & 15);
                bfr[i] = *(const bf16x8*)((char*)Bs + brow * (BK * 2) + kel * 2);
            }
            #pragma unroll
            for (int mi = 0; mi < 4; ++mi) {
                #pragma unroll
                for (int ni = 0; ni < 4; ++ni) {
                    acc[mi][ni] = __builtin_amdgcn_mfma_f32_16x16x32_bf16(
                        af[mi], bfr[ni], acc[mi][ni], 0, 0, 0);
                }
            }
        }
    }

    // epilogue: D element (row=(lane>>4)*4+r, col=lane&15)  [m89-verified]
    const int cl = lane & 15;
    const int r0 = (lane >> 4) * 4;
    #pragma unroll
    for (int ni = 0; ni < 4; ++ni) {
        const int n = n0 + wc * 64 + ni * 16 + cl;
        const float bvv = bias[n];
        #pragma unroll
        for (int mi = 0; mi < 4; ++mi) {
            const int m = m0 + wr * 64 + mi * 16 + r0;
            #pragma unroll
            for (int r = 0; r < 4; ++r) {
                C[(size_t)(m + r) * N_TOTAL + n] = acc[mi][ni][r] + bvv;
            }
        }
    }
}

// ---------------- fallback: round-1 single kernel (known-good, 95.6 us) -----
__device__ __forceinline__ short f2bf(float f) {
    unsigned u = __builtin_bit_cast(unsigned, f);
    u += 0x7fffu + ((u >> 16) & 1u);
    return (short)(u >> 16);
}

__global__ __launch_bounds__(256) void fb_gemm_bias_kernel(
    const float* __restrict__ X, const float* __restrict__ W,
    const float* __restrict__ bias, float* __restrict__ C)
{
    __shared__ short As[BM * BK];
    __shared__ short Bs[BN * BK];

    const int tid  = threadIdx.x;
    const int lane = tid & 63;
    const int wave = tid >> 6;
    const int wr = wave >> 1;
    const int wc = wave & 1;

    const int bid  = blockIdx.x;
    const int work = (bid & 7) * (NWG / 8) + (bid >> 3);
    const int bm = work >> 3;
    const int bn = work & 7;
    const int m0 = bm * BM, n0 = bn * BN;

    const int srow  = tid >> 4;
    const int scol4 = tid & 15;

    f32x4 acc[4][4] = {};
    char* const Ab = (char*)As;
    char* const Bb = (char*)Bs;

    for (int k0 = 0; k0 < K_TOTAL; k0 += BK) {
        __syncthreads();
        #pragma unroll
        for (int pass = 0; pass < 8; ++pass) {
            const int row = srow + pass * 16;
            const int off = (row * (BK * 2) + scol4 * 8) ^ ((row & 7) << 4);
            {
                const f32x4 v = *(const f32x4*)(X + (size_t)(m0 + row) * K_TOTAL + k0 + scol4 * 4);
                bf16x4 b;
                b[0] = f2bf(v[0]); b[1] = f2bf(v[1]); b[2] = f2bf(v[2]); b[3] = f2bf(v[3]);
                *(bf16x4*)(Ab + off) = b;
            }
            {
                const f32x4 v = *(const f32x4*)(W + (size_t)(n0 + row) * K_TOTAL + k0 + scol4 * 4);
                bf16x4 b;
                b[0] = f2bf(v[0]); b[1] = f2bf(v[1]); b[2] = f2bf(v[2]); b[3] = f2bf(v[3]);
                *(bf16x4*)(Bb + off) = b;
            }
        }
        __syncthreads();

        #pragma unroll
        for (int ks = 0; ks < 2; ++ks) {
            const int kel = ks * 32 + ((lane >> 4) << 3);
            bf16x8 af[4], bfr[4];
            #pragma unroll
            for (int i = 0; i < 4; ++i) {
                const int arow = wr * 64 + i * 16 + (lane & 15);
                af[i]  = *(const bf16x8*)(Ab + ((arow * (BK * 2) + kel * 2) ^ ((arow & 7) << 4)));
                const int brow = wc * 64 + i * 16 + (lane & 15);
                bfr[i] = *(const bf16x8*)(Bb + ((brow * (BK * 2) + kel * 2) ^ ((brow & 7) << 4)));
            }
            #pragma unroll
            for (int mi = 0; mi < 4; ++mi) {
                #pragma unroll
                for (int ni = 0; ni < 4; ++ni) {
                    acc[mi][ni] = __builtin_amdgcn_mfma_f32_16x16x32_bf16(
                        af[mi], bfr[ni], acc[mi][ni], 0, 0, 0);
                }
            }
        }
    }

    const int cl = lane & 15;
    const int r0 = (lane >> 4) * 4;
    #pragma unroll
    for (int ni = 0; ni < 4; ++ni) {
        const int n = n0 + wc * 64 + ni * 16 + cl;
        const float bvv = bias[n];
        #pragma unroll
        for (int mi = 0; mi < 4; ++mi) {
            const int m = m0 + wr * 64 + mi * 16 + r0;
            #pragma unroll
            for (int r = 0; r < 4; ++r) {
                C[(size_t)(m + r) * N_TOTAL + n] = acc[mi][ni][r] + bvv;
            }
        }
    }
}

extern "C" void kernel_launch(void* const* d_in, const int* in_sizes, int n_in,
                              void* d_out, int out_size, void* d_ws, size_t ws_size,
                              hipStream_t stream) {
    // inputs: 0:X 1:Wq 2:bq 3:Wk 4:bk 5:Wv 6:bv
    // softmax rows sum to 1 => out = X @ Wv^T + bv exactly.
    const float* X  = (const float*)d_in[0];
    const float* Wv = (const float*)d_in[5];
    const float* bv = (const float*)d_in[6];
    float* out = (float*)d_out;

    const size_t XB_BYTES = (size_t)M_TOTAL * K_TOTAL * 2;   // 32 MiB
    const size_t WB_BYTES = (size_t)N_TOTAL * K_TOTAL * 2;   // 2 MiB

    if (ws_size >= XB_BYTES + WB_BYTES) {
        unsigned short* Xb = (unsigned short*)d_ws;
        unsigned short* Wb = (unsigned short*)((char*)d_ws + XB_BYTES);
        cvt_bf16_kernel<<<dim3(M_TOTAL * K_TOTAL / 8 / 256), dim3(256), 0, stream>>>(
            X, (uint4*)Xb, M_TOTAL * K_TOTAL / 8);
        cvt_bf16_kernel<<<dim3(N_TOTAL * K_TOTAL / 8 / 256), dim3(256), 0, stream>>>(
            Wv, (uint4*)Wb, N_TOTAL * K_TOTAL / 8);
        gemm_lds_kernel<<<dim3(NWG), dim3(256), 0, stream>>>(Xb, Wb, bv, out);
    } else {
        fb_gemm_bias_kernel<<<dim3(NWG), dim3(256), 0, stream>>>(X, Wv, bv, out);
    }
}

// Round 4
// 62.085 us; speedup vs baseline: 1.7431x; 1.2437x over previous
//
#include <hip/hip_runtime.h>
#include <stdint.h>

#define M_TOTAL 16384
#define N_TOTAL 1024
#define K_TOTAL 1024

using f32x4  = __attribute__((ext_vector_type(4))) float;
using bf16x8 = __attribute__((ext_vector_type(8))) short;
using bf16x4 = __attribute__((ext_vector_type(4))) short;

__device__ __forceinline__ unsigned packrne(float x, float y) {
    unsigned ux = __builtin_bit_cast(unsigned, x);
    unsigned uy = __builtin_bit_cast(unsigned, y);
    ux += 0x7fffu + ((ux >> 16) & 1u);
    uy += 0x7fffu + ((uy >> 16) & 1u);
    return (ux >> 16) | (uy & 0xffff0000u);
}

// ---------------- kernel 1: fused fp32->bf16 convert of X and Wv ------------
#define N8X (M_TOTAL * K_TOTAL / 8)   // 2097152
#define N8W (N_TOTAL * K_TOTAL / 8)   // 131072
__global__ __launch_bounds__(256) void cvt2_kernel(
    const float* __restrict__ X, const float* __restrict__ W,
    uint4* __restrict__ Xb, uint4* __restrict__ Wb)
{
    const int i = blockIdx.x * 256 + threadIdx.x;
    const float* src; uint4* dst; int idx;
    if (i < N8X) { src = X; dst = Xb; idx = i; }
    else         { src = W; dst = Wb; idx = i - N8X; }
    const f32x4* p = (const f32x4*)src + (size_t)idx * 2;
    const f32x4 a = p[0], b = p[1];
    uint4 r;
    r.x = packrne(a[0], a[1]);
    r.y = packrne(a[2], a[3]);
    r.z = packrne(b[0], b[1]);
    r.w = packrne(b[2], b[3]);
    dst[idx] = r;
}

// ---------------- kernel 2: 256x256 counted-vmcnt pipelined bf16 GEMM -------
// C[m][n] = sum_k Xb[m][k]*Wb[n][k] + bias[n].
// 8 waves (2Mx4N), wave-tile 128x64, BK=64 -> 64 MFMA/wave/tile.
// LDS 128KB: A[2] 32KB + B[2] 32KB, XOR-swizzled (slot = kg ^ (row&7)),
// achieved via pre-swizzled global source (linear gload_lds dest) + swizzled
// ds_read. Schedule per tile: barrier / stage(t+1) / vmcnt(8) counted /
// barrier / 4 quadrant phases (ds_read + 16 MFMA each, setprio-wrapped).
#define BM 256
#define BN 256
#define BK 64
#define NTILES (K_TOTAL / BK)       // 16
#define NBM (M_TOTAL / BM)          // 64
#define NBN (N_TOTAL / BN)          // 4
#define NWG (NBM * NBN)             // 256

__global__ __launch_bounds__(512) void gemm8_kernel(
    const unsigned short* __restrict__ Xb, const unsigned short* __restrict__ Wb,
    const float* __restrict__ bias, float* __restrict__ C)
{
    __shared__ short smem[65536];   // 128 KB: A0@0 A1@32768 B0@65536 B1@98304 (bytes)

    const int tid  = threadIdx.x;
    const int lane = tid & 63;
    const int wave = tid >> 6;      // 0..7
    const int wr = wave >> 2;       // 0..1 : 128-row strip
    const int wc = wave & 3;        // 0..3 : 64-col strip

    // XCD-chunked swizzle (256 blocks % 8 == 0): the 4 bn-blocks of one
    // bm-panel co-resident on one XCD (X panel fetched ~once; round-2/3 verified).
    const int bid  = blockIdx.x;
    const int work = (bid & 7) * (NWG / 8) + (bid >> 3);
    const int bm = work >> 2;
    const int bn = work & 3;
    const int m0 = bm * BM, n0 = bn * BN;

    // staging geometry: issue j covers 64 rows; wave w covers rows w*8..w*8+7;
    // HW scatters lane i at ldsbase + i*16 (linear). Source k-group is
    // pre-swizzled so that LDS slot s of row r holds kg = s ^ (r&7).
    const int srow64 = wave * 8 + (lane >> 3);                 // row in 64-row stripe
    const int kge    = ((lane & 7) ^ ((lane >> 3) & 7)) * 8;   // swizzled k elem offset

    f32x4 acc[8][4] = {};

    auto stage_tile = [&](int t, int dbuf) {
        const int k0 = t * BK;
        #pragma unroll
        for (int j = 0; j < 4; ++j) {
            __builtin_amdgcn_global_load_lds(
                (const __attribute__((address_space(1))) void*)
                    (Xb + (size_t)(m0 + j * 64 + srow64) * K_TOTAL + k0 + kge),
                (__attribute__((address_space(3))) void*)
                    ((char*)smem + dbuf * 32768 + j * 8192 + wave * 1024),
                16, 0, 0);
        }
        #pragma unroll
        for (int j = 0; j < 4; ++j) {
            __builtin_amdgcn_global_load_lds(
                (const __attribute__((address_space(1))) void*)
                    (Wb + (size_t)(n0 + j * 64 + srow64) * K_TOTAL + k0 + kge),
                (__attribute__((address_space(3))) void*)
                    ((char*)smem + 65536 + dbuf * 32768 + j * 8192 + wave * 1024),
                16, 0, 0);
        }
    };

    const int cl = lane & 15;
    const int kb = lane >> 4;       // 0..3: k-group within a 32-wide k-half

    auto compute_tile = [&](int dbuf) {
        const char* Abase = (const char*)smem + dbuf * 32768;
        const char* Bbase = (const char*)smem + 65536 + dbuf * 32768;
        bf16x8 aF[4][2], bF0[2][2], bF1[2][2];

        // ---- phase 1: A rows 0-63 + B cols 0-31 ; MFMA Q(0,0) ----
        #pragma unroll
        for (int i = 0; i < 4; ++i) {
            const int ar = wr * 128 + i * 16 + cl;
            const int rs = ar & 7;
            aF[i][0] = *(const bf16x8*)(Abase + ar * 128 + ((kb       ^ rs) << 4));
            aF[i][1] = *(const bf16x8*)(Abase + ar * 128 + (((kb + 4) ^ rs) << 4));
        }
        #pragma unroll
        for (int j = 0; j < 2; ++j) {
            const int br = wc * 64 + j * 16 + cl;
            const int rs = br & 7;
            bF0[j][0] = *(const bf16x8*)(Bbase + br * 128 + ((kb       ^ rs) << 4));
            bF0[j][1] = *(const bf16x8*)(Bbase + br * 128 + (((kb + 4) ^ rs) << 4));
        }
        __builtin_amdgcn_s_setprio(1);
        #pragma unroll
        for (int i = 0; i < 4; ++i)
            #pragma unroll
            for (int j = 0; j < 2; ++j) {
                acc[i][j] = __builtin_amdgcn_mfma_f32_16x16x32_bf16(aF[i][0], bF0[j][0], acc[i][j], 0, 0, 0);
                acc[i][j] = __builtin_amdgcn_mfma_f32_16x16x32_bf16(aF[i][1], bF0[j][1], acc[i][j], 0, 0, 0);
            }
        __builtin_amdgcn_s_setprio(0);

        // ---- phase 2: B cols 32-63 ; MFMA Q(0,1) ----
        #pragma unroll
        for (int j = 0; j < 2; ++j) {
            const int br = wc * 64 + 32 + j * 16 + cl;
            const int rs = br & 7;
            bF1[j][0] = *(const bf16x8*)(Bbase + br * 128 + ((kb       ^ rs) << 4));
            bF1[j][1] = *(const bf16x8*)(Bbase + br * 128 + (((kb + 4) ^ rs) << 4));
        }
        __builtin_amdgcn_s_setprio(1);
        #pragma unroll
        for (int i = 0; i < 4; ++i)
            #pragma unroll
            for (int j = 0; j < 2; ++j) {
                acc[i][2 + j] = __builtin_amdgcn_mfma_f32_16x16x32_bf16(aF[i][0], bF1[j][0], acc[i][2 + j], 0, 0, 0);
                acc[i][2 + j] = __builtin_amdgcn_mfma_f32_16x16x32_bf16(aF[i][1], bF1[j][1], acc[i][2 + j], 0, 0, 0);
            }
        __builtin_amdgcn_s_setprio(0);

        // ---- phase 3: A rows 64-127 (reuse aF regs) ; MFMA Q(1,1) ----
        #pragma unroll
        for (int i = 0; i < 4; ++i) {
            const int ar = wr * 128 + 64 + i * 16 + cl;
            const int rs = ar & 7;
            aF[i][0] = *(const bf16x8*)(Abase + ar * 128 + ((kb       ^ rs) << 4));
            aF[i][1] = *(const bf16x8*)(Abase + ar * 128 + (((kb + 4) ^ rs) << 4));
        }
        __builtin_amdgcn_s_setprio(1);
        #pragma unroll
        for (int i = 0; i < 4; ++i)
            #pragma unroll
            for (int j = 0; j < 2; ++j) {
                acc[4 + i][2 + j] = __builtin_amdgcn_mfma_f32_16x16x32_bf16(aF[i][0], bF1[j][0], acc[4 + i][2 + j], 0, 0, 0);
                acc[4 + i][2 + j] = __builtin_amdgcn_mfma_f32_16x16x32_bf16(aF[i][1], bF1[j][1], acc[4 + i][2 + j], 0, 0, 0);
            }
        __builtin_amdgcn_s_setprio(0);

        // ---- phase 4: MFMA Q(1,0) (all frags already in regs) ----
        __builtin_amdgcn_s_setprio(1);
        #pragma unroll
        for (int i = 0; i < 4; ++i)
            #pragma unroll
            for (int j = 0; j < 2; ++j) {
                acc[4 + i][j] = __builtin_amdgcn_mfma_f32_16x16x32_bf16(aF[i][0], bF0[j][0], acc[4 + i][j], 0, 0, 0);
                acc[4 + i][j] = __builtin_amdgcn_mfma_f32_16x16x32_bf16(aF[i][1], bF0[j][1], acc[4 + i][j], 0, 0, 0);
            }
        __builtin_amdgcn_s_setprio(0);
    };

    // ---- pipeline ----
    stage_tile(0, 0);
    #pragma unroll 1
    for (int t = 0; t < NTILES - 1; ++t) {
        const int d = t & 1;
        // B1: all waves done reading buf d^1 (tile t-1) -> safe to overwrite
        __builtin_amdgcn_sched_barrier(0);
        __builtin_amdgcn_s_barrier();
        __builtin_amdgcn_sched_barrier(0);
        stage_tile(t + 1, d ^ 1);
        // counted wait: my 8 new loads stay in flight; tile t's loads landed
        asm volatile("s_waitcnt vmcnt(8)" ::: "memory");
        __builtin_amdgcn_sched_barrier(0);
        __builtin_amdgcn_s_barrier();   // B2: ALL waves' tile-t loads landed
        __builtin_amdgcn_sched_barrier(0);
        compute_tile(d);
    }
    // tail: tile 15 from buf 1
    __builtin_amdgcn_sched_barrier(0);
    asm volatile("s_waitcnt vmcnt(0)" ::: "memory");
    __builtin_amdgcn_s_barrier();
    __builtin_amdgcn_sched_barrier(0);
    compute_tile(1);

    // ---- epilogue: D element (row=(lane>>4)*4+r, col=lane&15) [m89] ----
    const int r0 = (lane >> 4) * 4;
    #pragma unroll
    for (int ni = 0; ni < 4; ++ni) {
        const int n = n0 + wc * 64 + ni * 16 + cl;
        const float bvv = bias[n];
        #pragma unroll
        for (int mi = 0; mi < 8; ++mi) {
            const int m = m0 + wr * 128 + mi * 16 + r0;
            #pragma unroll
            for (int r = 0; r < 4; ++r)
                C[(size_t)(m + r) * N_TOTAL + n] = acc[mi][ni][r] + bvv;
        }
    }
}

// ---------------- fallback: round-1 single kernel (known-good) --------------
__device__ __forceinline__ short f2bf(float f) {
    unsigned u = __builtin_bit_cast(unsigned, f);
    u += 0x7fffu + ((u >> 16) & 1u);
    return (short)(u >> 16);
}

#define FBM 128
#define FBN 128
#define FNWG ((M_TOTAL / FBM) * (N_TOTAL / FBN))   // 1024

__global__ __launch_bounds__(256) void fb_gemm_bias_kernel(
    const float* __restrict__ X, const float* __restrict__ W,
    const float* __restrict__ bias, float* __restrict__ C)
{
    __shared__ short As[FBM * BK];
    __shared__ short Bs[FBN * BK];

    const int tid  = threadIdx.x;
    const int lane = tid & 63;
    const int wave = tid >> 6;
    const int wr = wave >> 1;
    const int wc = wave & 1;

    const int bid  = blockIdx.x;
    const int work = (bid & 7) * (FNWG / 8) + (bid >> 3);
    const int bm = work >> 3;
    const int bn = work & 7;
    const int m0 = bm * FBM, n0 = bn * FBN;

    const int srow  = tid >> 4;
    const int scol4 = tid & 15;

    f32x4 acc[4][4] = {};
    char* const Ab = (char*)As;
    char* const Bb = (char*)Bs;

    for (int k0 = 0; k0 < K_TOTAL; k0 += BK) {
        __syncthreads();
        #pragma unroll
        for (int pass = 0; pass < 8; ++pass) {
            const int row = srow + pass * 16;
            const int off = (row * (BK * 2) + scol4 * 8) ^ ((row & 7) << 4);
            {
                const f32x4 v = *(const f32x4*)(X + (size_t)(m0 + row) * K_TOTAL + k0 + scol4 * 4);
                bf16x4 b;
                b[0] = f2bf(v[0]); b[1] = f2bf(v[1]); b[2] = f2bf(v[2]); b[3] = f2bf(v[3]);
                *(bf16x4*)(Ab + off) = b;
            }
            {
                const f32x4 v = *(const f32x4*)(W + (size_t)(n0 + row) * K_TOTAL + k0 + scol4 * 4);
                bf16x4 b;
                b[0] = f2bf(v[0]); b[1] = f2bf(v[1]); b[2] = f2bf(v[2]); b[3] = f2bf(v[3]);
                *(bf16x4*)(Bb + off) = b;
            }
        }
        __syncthreads();

        #pragma unroll
        for (int ks = 0; ks < 2; ++ks) {
            const int kel = ks * 32 + ((lane >> 4) << 3);
            bf16x8 af[4], bfr[4];
            #pragma unroll
            for (int i = 0; i < 4; ++i) {
                const int arow = wr * 64 + i * 16 + (lane & 15);
                af[i]  = *(const bf16x8*)(Ab + ((arow * (BK * 2) + kel * 2) ^ ((arow & 7) << 4)));
                const int brow = wc * 64 + i * 16 + (lane & 15);
                bfr[i] = *(const bf16x8*)(Bb + ((brow * (BK * 2) + kel * 2) ^ ((brow & 7) << 4)));
            }
            #pragma unroll
            for (int mi = 0; mi < 4; ++mi)
                #pragma unroll
                for (int ni = 0; ni < 4; ++ni)
                    acc[mi][ni] = __builtin_amdgcn_mfma_f32_16x16x32_bf16(
                        af[mi], bfr[ni], acc[mi][ni], 0, 0, 0);
        }
    }

    const int cl = lane & 15;
    const int r0 = (lane >> 4) * 4;
    #pragma unroll
    for (int ni = 0; ni < 4; ++ni) {
        const int n = n0 + wc * 64 + ni * 16 + cl;
        const float bvv = bias[n];
        #pragma unroll
        for (int mi = 0; mi < 4; ++mi) {
            const int m = m0 + wr * 64 + mi * 16 + r0;
            #pragma unroll
            for (int r = 0; r < 4; ++r)
                C[(size_t)(m + r) * N_TOTAL + n] = acc[mi][ni][r] + bvv;
        }
    }
}

extern "C" void kernel_launch(void* const* d_in, const int* in_sizes, int n_in,
                              void* d_out, int out_size, void* d_ws, size_t ws_size,
                              hipStream_t stream) {
    // inputs: 0:X 1:Wq 2:bq 3:Wk 4:bk 5:Wv 6:bv
    // softmax rows sum to 1 => out = X @ Wv^T + bv exactly.
    const float* X  = (const float*)d_in[0];
    const float* Wv = (const float*)d_in[5];
    const float* bv = (const float*)d_in[6];
    float* out = (float*)d_out;

    const size_t XB_BYTES = (size_t)M_TOTAL * K_TOTAL * 2;   // 32 MiB
    const size_t WB_BYTES = (size_t)N_TOTAL * K_TOTAL * 2;   // 2 MiB

    if (ws_size >= XB_BYTES + WB_BYTES) {
        unsigned short* Xb = (unsigned short*)d_ws;
        unsigned short* Wb = (unsigned short*)((char*)d_ws + XB_BYTES);
        cvt2_kernel<<<dim3((N8X + N8W) / 256), dim3(256), 0, stream>>>(
            X, Wv, (uint4*)Xb, (uint4*)Wb);
        gemm8_kernel<<<dim3(NWG), dim3(512), 0, stream>>>(Xb, Wb, bv, out);
    } else {
        fb_gemm_bias_kernel<<<dim3(FNWG), dim3(256), 0, stream>>>(X, Wv, bv, out);
    }
}